// Round 15
// baseline (3605.334 us; speedup 1.0000x reference)
//
#include <hip/hip_runtime.h>

#define BATCH  131072
#define NSTEPS 100

typedef _Float16 half8  __attribute__((ext_vector_type(8)));
typedef float    f32x4  __attribute__((ext_vector_type(4)));
typedef float    f32x2  __attribute__((ext_vector_type(2)));
typedef unsigned u32x4  __attribute__((ext_vector_type(4)));

__device__ __forceinline__ unsigned pkh2(float a, float b) {
    return __builtin_bit_cast(unsigned, __builtin_amdgcn_cvt_pkrtz(a, b));
}

// Trans-pipe sincos (R10-proven): exact revolutions identity,
// sin(z) = sin(2pi * fract(z/2pi)). 2 full-rate + 2 trans ops.
__device__ __forceinline__ void tsincos(float z, float& s, float& c) {
    float u = __builtin_amdgcn_fractf(z * 0.15915494309189535f);
    s = __builtin_amdgcn_sinf(u);
    c = __builtin_amdgcn_cosf(u);
}

// ---------------------------------------------------------------------------
// R14 hybrid base (trans+VALU sincos split) + OCCUPANCY 2->3 waves/SIMD:
//  - layer-0 A-frags demoted to per-step LDS reads (-32 regs; 8 contiguous
//    ds_read_b128/step, conflict-free, ~96 DS-cyc hidden under compute)
//  - W4 read from LDS at use in L3 epilogue (-16 regs)
//  - __launch_bounds__(256,3): unified VGPR/AGPR cap 170/wave; demand ~142
//    -> fits with margin (R8 spill mode needs ~50+ dwords over; impossible).
// Mechanism: R9/R10/R14 triangulate that sincos latency (trans or poly) sits
// on the per-wave critical path and 2 waves/SIMD cannot fill the bubbles;
// the 3rd wave supplies the missing independent work.
//
// Wave owns 16 samples; lane (c=l&15, g=l>>4). B-frag (kt,qq,r) holds neuron
// n = 32kt+16qq+4g+r; C layout row = 16mt+4g+r makes lane g's C-quads exactly
// its next-layer B-frags (HW-verified R5-R14).
// ---------------------------------------------------------------------------
extern "C" __global__ void __launch_bounds__(256, 3)
fbsnn_kernel(const float* __restrict__ W0, const float* __restrict__ b0,
             const float* __restrict__ W1, const float* __restrict__ b1,
             const float* __restrict__ W2, const float* __restrict__ b2,
             const float* __restrict__ W3, const float* __restrict__ b3,
             const float* __restrict__ W4, const float* __restrict__ b4,
             const float* __restrict__ y0p, const float* __restrict__ dW,
             float* __restrict__ slots)
{
    __shared__ unsigned ldsA[6144];    // A-frags, u32-packed f16 pairs (24.5 KB)
    __shared__ float    ldsWA[64];     // L0 t-weights, pairs per (g,qi,h)
    __shared__ float    ldsWB[64];     // L0 y-weights
    __shared__ float    ldsB0[64];     // L0 bias
    __shared__ float    ldsBias[192];  // [li][mt][g][r]
    __shared__ float    ldsW4[64];     // [mt][g][r]

    const int tid = threadIdx.x;
    const int l   = tid & 63;
    const int wu  = tid >> 6;
    const int c   = l & 15;
    const int g   = l >> 4;
    const int sample = blockIdx.x * 64 + wu * 16 + c;

    const float DT = 0.01f, SQDT = 0.1f;

    // ================= prep: stage weights into LDS =================
    {
        for (int idx = tid; idx < 6144; idx += 256) {
            int w   = idx & 3;
            int lam = (idx >> 2) & 63;
            int f   = (idx >> 8) & 7;
            int li  = idx >> 11;
            const float* Wsl = (li == 0) ? W1 : (li == 1) ? W2 : W3;
            int cc = lam & 15, gg = lam >> 4;
            int mt = f >> 1, kt = f & 1;
            int m = 16 * mt + cc;
            int k = 32 * kt + 16 * (w >> 1) + 4 * gg + ((2 * w) & 3);
            const float* Wp = Wsl + m * 64 + k;
            ldsA[(8 * li + f) * 256 + lam * 4 + w] = pkh2(Wp[0], Wp[1]);
        }
        if (tid < 32) {
            int gg = tid >> 3, qi = (tid >> 1) & 3, h = tid & 1;
            int n0 = 32 * (qi >> 1) + 16 * (qi & 1) + 4 * gg + 2 * h;
            ldsWA[2 * tid]     = W0[2 * n0];
            ldsWA[2 * tid + 1] = W0[2 * n0 + 2];
            ldsWB[2 * tid]     = W0[2 * n0 + 1];
            ldsWB[2 * tid + 1] = W0[2 * n0 + 3];
            ldsB0[2 * tid]     = b0[n0];
            ldsB0[2 * tid + 1] = b0[n0 + 1];
        }
        if (tid < 192) {
            int li = tid >> 6, mt = (tid >> 4) & 3, gg = (tid >> 2) & 3, r = tid & 3;
            ldsBias[tid] = ((li == 0) ? b1 : (li == 1) ? b2 : b3)[16 * mt + 4 * gg + r];
        }
        if (tid < 64) {
            int mt = tid >> 4, gg = (tid >> 2) & 3, r = tid & 3;
            ldsW4[tid] = W4[16 * mt + 4 * gg + r];
        }
    }
    __syncthreads();   // only barrier; LDS is read-only below

    // ---- persistent A-frags for layers 1,2 ONLY (64 regs); layer 0 is
    // re-read from LDS each step (occupancy trade) ----
    half8 AF[2][4][2];
    #pragma unroll
    for (int li = 1; li < 3; ++li)
        #pragma unroll
        for (int mt = 0; mt < 4; ++mt)
            #pragma unroll
            for (int kt = 0; kt < 2; ++kt)
                AF[li - 1][mt][kt] =
                    *(const half8*)&ldsA[(8 * li + 2 * mt + kt) * 256 + l * 4];

    const float b4v = b4[0];
    float y = y0p[0];
    float t = 0.0f;
    float Y0 = 0.f, dY0 = 0.f, q0 = 0.f, Z0 = 0.f, dws = 0.f, loss = 0.f;

    #pragma unroll 1
    for (int s = 0; s <= NSTEPS; ++s) {
        float dwv = 0.0f;
        if (s < NSTEPS) dwv = dW[s * BATCH + sample];   // prefetch early

        // ============ layer 0: build B-frags in registers ============
        // h=1 pair -> trans pipe (issued first), h=0 pair -> OCML poly.
        half8 BX[2], BV[2];
        #pragma unroll
        for (int kt = 0; kt < 2; ++kt) {
            u32x4 ux, uv;
            #pragma unroll
            for (int qq = 0; qq < 2; ++qq) {
                int qi = 2 * kt + qq;
                int o0 = g * 8 + qi * 2;         // h = 0
                int o1 = o0 + 1;                 // h = 1
                f32x2 wa1 = *(const f32x2*)&ldsWA[2 * o1];
                f32x2 wb1 = *(const f32x2*)&ldsWB[2 * o1];
                f32x2 bb1 = *(const f32x2*)&ldsB0[2 * o1];
                float z2 = fmaf(wa1[0], t, fmaf(wb1[0], y, bb1[0]));
                float z3 = fmaf(wa1[1], t, fmaf(wb1[1], y, bb1[1]));
                float s2, c2, s3, c3;
                tsincos(z2, s2, c2);             // trans pipe, issue first
                tsincos(z3, s3, c3);
                f32x2 wa0 = *(const f32x2*)&ldsWA[2 * o0];
                f32x2 wb0 = *(const f32x2*)&ldsWB[2 * o0];
                f32x2 bb0 = *(const f32x2*)&ldsB0[2 * o0];
                float z0 = fmaf(wa0[0], t, fmaf(wb0[0], y, bb0[0]));
                float z1 = fmaf(wa0[1], t, fmaf(wb0[1], y, bb0[1]));
                float s0, c0, s1, c1;
                __sincosf(z0, &s0, &c0);         // VALU poly, overlaps trans
                __sincosf(z1, &s1, &c1);
                ux[2 * qq + 0] = pkh2(s0, s1);
                ux[2 * qq + 1] = pkh2(s2, s3);
                uv[2 * qq + 0] = pkh2(c0 * wb0[0], c1 * wb0[1]);
                uv[2 * qq + 1] = pkh2(c2 * wb1[0], c3 * wb1[1]);
            }
            BX[kt] = __builtin_bit_cast(half8, ux);
            BV[kt] = __builtin_bit_cast(half8, uv);
        }

        // ============ hidden layers 1..3 ============
        float Y1 = 0.f, dY1 = 0.f;
        #pragma unroll
        for (int li = 0; li < 3; ++li) {
            f32x4 ax[4], av[4];
            #pragma unroll
            for (int mt = 0; mt < 4; ++mt) {
                half8 a0, a1;
                if (li == 0) {   // demoted layer: read frags from LDS
                    a0 = *(const half8*)&ldsA[(2 * mt + 0) * 256 + l * 4];
                    a1 = *(const half8*)&ldsA[(2 * mt + 1) * 256 + l * 4];
                } else {
                    a0 = AF[li - 1][mt][0];
                    a1 = AF[li - 1][mt][1];
                }
                f32x4 ci = *(const f32x4*)&ldsBias[((li * 4 + mt) * 4 + g) * 4];
                f32x4 a = __builtin_amdgcn_mfma_f32_16x16x32_f16(a0, BX[0], ci, 0, 0, 0);
                a = __builtin_amdgcn_mfma_f32_16x16x32_f16(a1, BX[1], a, 0, 0, 0);
                ax[mt] = a;
                f32x4 v = {0.f, 0.f, 0.f, 0.f};
                v = __builtin_amdgcn_mfma_f32_16x16x32_f16(a0, BV[0], v, 0, 0, 0);
                v = __builtin_amdgcn_mfma_f32_16x16x32_f16(a1, BV[1], v, 0, 0, 0);
                av[mt] = v;
            }
            if (li < 2) {
                u32x4 nx[2], nv[2];
                #pragma unroll
                for (int mt = 0; mt < 4; ++mt) {
                    float s2, c2, s3, c3;
                    tsincos(ax[mt][2], s2, c2);  // trans pipe, issue first
                    tsincos(ax[mt][3], s3, c3);
                    float s0, c0, s1, c1;
                    __sincosf(ax[mt][0], &s0, &c0);  // VALU poly overlaps
                    __sincosf(ax[mt][1], &s1, &c1);
                    nx[mt >> 1][2 * (mt & 1) + 0] = pkh2(s0, s1);
                    nx[mt >> 1][2 * (mt & 1) + 1] = pkh2(s2, s3);
                    nv[mt >> 1][2 * (mt & 1) + 0] = pkh2(c0 * av[mt][0], c1 * av[mt][1]);
                    nv[mt >> 1][2 * (mt & 1) + 1] = pkh2(c2 * av[mt][2], c3 * av[mt][3]);
                }
                BX[0] = __builtin_bit_cast(half8, nx[0]);
                BX[1] = __builtin_bit_cast(half8, nx[1]);
                BV[0] = __builtin_bit_cast(half8, nv[0]);
                BV[1] = __builtin_bit_cast(half8, nv[1]);
            } else {
                float sx = 0.f, sv = 0.f;
                #pragma unroll
                for (int mt = 0; mt < 4; ++mt) {
                    f32x4 wv4 = *(const f32x4*)&ldsW4[(mt * 4 + g) * 4];
                    float s2, c2, s3, c3;
                    tsincos(ax[mt][2], s2, c2);  // trans first
                    tsincos(ax[mt][3], s3, c3);
                    float s0, c0, s1, c1;
                    __sincosf(ax[mt][0], &s0, &c0);
                    __sincosf(ax[mt][1], &s1, &c1);
                    sx = fmaf(wv4[0], s0, sx);
                    sx = fmaf(wv4[1], s1, sx);
                    sx = fmaf(wv4[2], s2, sx);
                    sx = fmaf(wv4[3], s3, sx);
                    sv = fmaf(wv4[0], c0 * av[mt][0], sv);
                    sv = fmaf(wv4[1], c1 * av[mt][1], sv);
                    sv = fmaf(wv4[2], c2 * av[mt][2], sv);
                    sv = fmaf(wv4[3], c3 * av[mt][3], sv);
                }
                sx += __shfl_xor(sx, 16); sx += __shfl_xor(sx, 32);
                sv += __shfl_xor(sv, 16); sv += __shfl_xor(sv, 32);
                Y1  = sx + b4v;
                dY1 = sv;
            }
        }

        // ============ trajectory / loss ============
        if (s > 0) {
            float Yt = Y0 - q0 * q0 * DT + Z0 * dws;
            float d  = Y1 - Yt;
            loss += d * d;
        }
        Y0 = Y1; dY0 = dY1;
        if (s < NSTEPS) {
            Z0  = 0.5f * dY0;
            q0  = -dY0;                 // exact (power-of-2 constants)
            dws = dwv * SQDT;
            y   = y + q0 * DT + 0.5f * dws;
            t   = t + DT;
        }
    }

    // terminal: (YN - yN^2)^2 + (dYN - 2*yN)^2
    float d1 = Y0 - y * y;
    float d2 = dY0 - 2.0f * y;
    loss += d1 * d1 + d2 * d2;

    // 4 g-lanes share a sample -> mask, then wave butterfly
    float lv = (g == 0) ? loss : 0.0f;
    #pragma unroll
    for (int off = 1; off < 64; off <<= 1)
        lv += __shfl_xor(lv, off);
    if (l == 0)
        atomicAdd(&slots[(blockIdx.x * 4 + wu) & 255], lv);
}

extern "C" __global__ void finish_kernel(const float* __restrict__ slots,
                                         float* __restrict__ out) {
    int l = threadIdx.x;   // 64 threads
    float v = slots[l] + slots[64 + l] + slots[128 + l] + slots[192 + l];
    #pragma unroll
    for (int off = 1; off < 64; off <<= 1)
        v += __shfl_xor(v, off);
    if (l == 0) out[0] = v * (1.0f / (float)BATCH);
}

extern "C" void kernel_launch(void* const* d_in, const int* in_sizes, int n_in,
                              void* d_out, int out_size, void* d_ws, size_t ws_size,
                              hipStream_t stream) {
    const float* W0  = (const float*)d_in[0];
    const float* b0  = (const float*)d_in[1];
    const float* W1  = (const float*)d_in[2];
    const float* b1  = (const float*)d_in[3];
    const float* W2  = (const float*)d_in[4];
    const float* b2  = (const float*)d_in[5];
    const float* W3  = (const float*)d_in[6];
    const float* b3  = (const float*)d_in[7];
    const float* W4  = (const float*)d_in[8];
    const float* b4  = (const float*)d_in[9];
    const float* y0p = (const float*)d_in[10];
    const float* dW  = (const float*)d_in[11];
    float* slots = (float*)d_ws;

    (void)hipMemsetAsync(d_ws, 0, 256 * sizeof(float), stream);

    dim3 grid(BATCH / 64);   // 2048 blocks x 4 independent waves (16 samples)
    dim3 block(256);
    fbsnn_kernel<<<grid, block, 0, stream>>>(W0, b0, W1, b1, W2, b2, W3, b3,
                                             W4, b4, y0p, dW, slots);
    finish_kernel<<<1, 64, 0, stream>>>(slots, (float*)d_out);
}

// Round 17
// 954.913 us; speedup vs baseline: 3.7756x; 3.7756x over previous
//
#include <hip/hip_runtime.h>

#define BATCH  131072
#define NSTEPS 100

typedef _Float16 half8  __attribute__((ext_vector_type(8)));
typedef float    f32x4  __attribute__((ext_vector_type(4)));
typedef float    f32x2  __attribute__((ext_vector_type(2)));
typedef unsigned u32x4  __attribute__((ext_vector_type(4)));

__device__ __forceinline__ unsigned pkh2(float a, float b) {
    return __builtin_bit_cast(unsigned, __builtin_amdgcn_cvt_pkrtz(a, b));
}

// ---------------------------------------------------------------------------
// R16 retry: identical structure, fixing R16's index bug (bias/W4 quad base
// used bob=g*4 -> 16g byte-quad offset instead of 4g; lanes g>0 read wrong
// bias/W4 -> absmax 14.4). Now bob = g + ob (quad index), used as
// ldsBias[(li*16 + mt*4 + bob)*4] == R15's (li*64 + mt*16 + 4g). Verified
// against R15's addressing term by term.
//
// R9 base (pure OCML __sincosf) + genuine 3 waves/SIMD:
//  * anti-LICM opaque index: every per-step LDS table read derives from an
//    asm-opaque zero (ob), so LICM can't hoist ~110 regs of loop-invariant
//    LDS loads into persistent registers (the R7/R8/R15 spill trigger).
//  * layer-0 A-frags per-step from LDS; layers 1-2 register-resident.
//  * per-mt interleaved MFMA+epilogue: ax/av 32 -> 8 regs.
//  Demand ~150 <= 170 = cap of __launch_bounds__(256,3).
// ---------------------------------------------------------------------------
extern "C" __global__ void __launch_bounds__(256, 3)
fbsnn_kernel(const float* __restrict__ W0, const float* __restrict__ b0,
             const float* __restrict__ W1, const float* __restrict__ b1,
             const float* __restrict__ W2, const float* __restrict__ b2,
             const float* __restrict__ W3, const float* __restrict__ b3,
             const float* __restrict__ W4, const float* __restrict__ b4,
             const float* __restrict__ y0p, const float* __restrict__ dW,
             float* __restrict__ slots)
{
    __shared__ unsigned ldsA[6144];    // A-frags, u32-packed f16 pairs (24.5 KB)
    __shared__ float    ldsWA[64];     // L0 t-weights, pairs per (g,qi,h)
    __shared__ float    ldsWB[64];     // L0 y-weights
    __shared__ float    ldsB0[64];     // L0 bias
    __shared__ float    ldsBias[192];  // [li][mt][g][r]
    __shared__ float    ldsW4[64];     // [mt][g][r]

    const int tid = threadIdx.x;
    const int l   = tid & 63;
    const int wu  = tid >> 6;
    const int c   = l & 15;
    const int g   = l >> 4;
    const int sample = blockIdx.x * 64 + wu * 16 + c;

    const float DT = 0.01f, SQDT = 0.1f;

    // ================= prep: stage weights into LDS =================
    {
        for (int idx = tid; idx < 6144; idx += 256) {
            int w   = idx & 3;
            int lam = (idx >> 2) & 63;
            int f   = (idx >> 8) & 7;
            int li  = idx >> 11;
            const float* Wsl = (li == 0) ? W1 : (li == 1) ? W2 : W3;
            int cc = lam & 15, gg = lam >> 4;
            int mt = f >> 1, kt = f & 1;
            int m = 16 * mt + cc;
            int k = 32 * kt + 16 * (w >> 1) + 4 * gg + ((2 * w) & 3);
            const float* Wp = Wsl + m * 64 + k;
            ldsA[(8 * li + f) * 256 + lam * 4 + w] = pkh2(Wp[0], Wp[1]);
        }
        if (tid < 32) {
            int gg = tid >> 3, qi = (tid >> 1) & 3, h = tid & 1;
            int n0 = 32 * (qi >> 1) + 16 * (qi & 1) + 4 * gg + 2 * h;
            ldsWA[2 * tid]     = W0[2 * n0];
            ldsWA[2 * tid + 1] = W0[2 * n0 + 2];
            ldsWB[2 * tid]     = W0[2 * n0 + 1];
            ldsWB[2 * tid + 1] = W0[2 * n0 + 3];
            ldsB0[2 * tid]     = b0[n0];
            ldsB0[2 * tid + 1] = b0[n0 + 1];
        }
        if (tid < 192) {
            int li = tid >> 6, mt = (tid >> 4) & 3, gg = (tid >> 2) & 3, r = tid & 3;
            ldsBias[tid] = ((li == 0) ? b1 : (li == 1) ? b2 : b3)[16 * mt + 4 * gg + r];
        }
        if (tid < 64) {
            int mt = tid >> 4, gg = (tid >> 2) & 3, r = tid & 3;
            ldsW4[tid] = W4[16 * mt + 4 * gg + r];
        }
    }
    __syncthreads();   // only barrier; LDS is read-only below

    // ---- persistent A-frags for layers 1,2 ONLY (64 regs) ----
    half8 AF[2][4][2];
    #pragma unroll
    for (int li = 1; li < 3; ++li)
        #pragma unroll
        for (int mt = 0; mt < 4; ++mt)
            #pragma unroll
            for (int kt = 0; kt < 2; ++kt)
                AF[li - 1][mt][kt] =
                    *(const half8*)&ldsA[(8 * li + 2 * mt + kt) * 256 + l * 4];

    const float b4v = b4[0];
    float y = y0p[0];
    float t = 0.0f;
    float Y0 = 0.f, dY0 = 0.f, q0 = 0.f, Z0 = 0.f, dws = 0.f, loss = 0.f;

    int ob = 0;   // opaque zero: refreshed every step so LICM can't hoist
                  // any LDS table load whose index depends on it.

    #pragma unroll 1
    for (int s = 0; s <= NSTEPS; ++s) {
        asm volatile("" : "+v"(ob));
        const int gob = g * 8 + ob;       // L0 table base (o = gob + qi*2 + h)
        const int lob = l * 4 + ob;       // A-frag lane base
        const int bob = g + ob;           // bias/W4 QUAD index (g, opaque)

        float dwv = 0.0f;
        if (s < NSTEPS) dwv = dW[s * BATCH + sample];   // prefetch early

        // ============ layer 0: build B-frags in registers ============
        half8 BX[2], BV[2];
        #pragma unroll
        for (int kt = 0; kt < 2; ++kt) {
            u32x4 ux, uv;
            #pragma unroll
            for (int qq = 0; qq < 2; ++qq) {
                int qi = 2 * kt + qq;
                #pragma unroll
                for (int h = 0; h < 2; ++h) {
                    int o = gob + qi * 2 + h;
                    f32x2 wa = *(const f32x2*)&ldsWA[2 * o];
                    f32x2 wb = *(const f32x2*)&ldsWB[2 * o];
                    f32x2 bb = *(const f32x2*)&ldsB0[2 * o];
                    float z0 = fmaf(wa[0], t, fmaf(wb[0], y, bb[0]));
                    float z1 = fmaf(wa[1], t, fmaf(wb[1], y, bb[1]));
                    float s0, c0, s1, c1;
                    __sincosf(z0, &s0, &c0);
                    __sincosf(z1, &s1, &c1);
                    ux[2 * qq + h] = pkh2(s0, s1);
                    uv[2 * qq + h] = pkh2(c0 * wb[0], c1 * wb[1]);
                }
            }
            BX[kt] = __builtin_bit_cast(half8, ux);
            BV[kt] = __builtin_bit_cast(half8, uv);
        }

        // ============ hidden layers 1..3 (per-mt interleaved) ============
        float Y1 = 0.f, dY1 = 0.f;
        #pragma unroll
        for (int li = 0; li < 3; ++li) {
            u32x4 nx[2], nv[2];
            float sx = 0.f, sv = 0.f;
            #pragma unroll
            for (int mt = 0; mt < 4; ++mt) {
                half8 a0, a1;
                if (li == 0) {   // layer-0 frags per-step from LDS (opaque idx)
                    a0 = *(const half8*)&ldsA[(2 * mt + 0) * 256 + lob];
                    a1 = *(const half8*)&ldsA[(2 * mt + 1) * 256 + lob];
                } else {
                    a0 = AF[li - 1][mt][0];
                    a1 = AF[li - 1][mt][1];
                }
                // quad index (li*16 + mt*4 + g), *4 floats -> matches R15
                f32x4 ci = *(const f32x4*)&ldsBias[(li * 16 + mt * 4 + bob) * 4];
                f32x4 ax = __builtin_amdgcn_mfma_f32_16x16x32_f16(a0, BX[0], ci, 0, 0, 0);
                ax = __builtin_amdgcn_mfma_f32_16x16x32_f16(a1, BX[1], ax, 0, 0, 0);
                f32x4 av = {0.f, 0.f, 0.f, 0.f};
                av = __builtin_amdgcn_mfma_f32_16x16x32_f16(a0, BV[0], av, 0, 0, 0);
                av = __builtin_amdgcn_mfma_f32_16x16x32_f16(a1, BV[1], av, 0, 0, 0);

                if (li < 2) {
                    float s0, c0, s1, c1, s2, c2, s3, c3;
                    __sincosf(ax[0], &s0, &c0);
                    __sincosf(ax[1], &s1, &c1);
                    __sincosf(ax[2], &s2, &c2);
                    __sincosf(ax[3], &s3, &c3);
                    nx[mt >> 1][2 * (mt & 1) + 0] = pkh2(s0, s1);
                    nx[mt >> 1][2 * (mt & 1) + 1] = pkh2(s2, s3);
                    nv[mt >> 1][2 * (mt & 1) + 0] = pkh2(c0 * av[0], c1 * av[1]);
                    nv[mt >> 1][2 * (mt & 1) + 1] = pkh2(c2 * av[2], c3 * av[3]);
                } else {
                    f32x4 wv4 = *(const f32x4*)&ldsW4[(mt * 4 + bob) * 4];
                    float s0, c0, s1, c1, s2, c2, s3, c3;
                    __sincosf(ax[0], &s0, &c0);
                    __sincosf(ax[1], &s1, &c1);
                    __sincosf(ax[2], &s2, &c2);
                    __sincosf(ax[3], &s3, &c3);
                    sx = fmaf(wv4[0], s0, sx);
                    sx = fmaf(wv4[1], s1, sx);
                    sx = fmaf(wv4[2], s2, sx);
                    sx = fmaf(wv4[3], s3, sx);
                    sv = fmaf(wv4[0], c0 * av[0], sv);
                    sv = fmaf(wv4[1], c1 * av[1], sv);
                    sv = fmaf(wv4[2], c2 * av[2], sv);
                    sv = fmaf(wv4[3], c3 * av[3], sv);
                }
            }
            if (li < 2) {
                BX[0] = __builtin_bit_cast(half8, nx[0]);
                BX[1] = __builtin_bit_cast(half8, nx[1]);
                BV[0] = __builtin_bit_cast(half8, nv[0]);
                BV[1] = __builtin_bit_cast(half8, nv[1]);
            } else {
                sx += __shfl_xor(sx, 16); sx += __shfl_xor(sx, 32);
                sv += __shfl_xor(sv, 16); sv += __shfl_xor(sv, 32);
                Y1  = sx + b4v;
                dY1 = sv;
            }
        }

        // ============ trajectory / loss ============
        if (s > 0) {
            float Yt = Y0 - q0 * q0 * DT + Z0 * dws;
            float d  = Y1 - Yt;
            loss += d * d;
        }
        Y0 = Y1; dY0 = dY1;
        if (s < NSTEPS) {
            Z0  = 0.5f * dY0;
            q0  = -dY0;                 // exact (power-of-2 constants)
            dws = dwv * SQDT;
            y   = y + q0 * DT + 0.5f * dws;
            t   = t + DT;
        }
    }

    // terminal: (YN - yN^2)^2 + (dYN - 2*yN)^2
    float d1 = Y0 - y * y;
    float d2 = dY0 - 2.0f * y;
    loss += d1 * d1 + d2 * d2;

    // 4 g-lanes share a sample -> mask, then wave butterfly
    float lv = (g == 0) ? loss : 0.0f;
    #pragma unroll
    for (int off = 1; off < 64; off <<= 1)
        lv += __shfl_xor(lv, off);
    if (l == 0)
        atomicAdd(&slots[(blockIdx.x * 4 + wu) & 255], lv);
}

extern "C" __global__ void finish_kernel(const float* __restrict__ slots,
                                         float* __restrict__ out) {
    int l = threadIdx.x;   // 64 threads
    float v = slots[l] + slots[64 + l] + slots[128 + l] + slots[192 + l];
    #pragma unroll
    for (int off = 1; off < 64; off <<= 1)
        v += __shfl_xor(v, off);
    if (l == 0) out[0] = v * (1.0f / (float)BATCH);
}

extern "C" void kernel_launch(void* const* d_in, const int* in_sizes, int n_in,
                              void* d_out, int out_size, void* d_ws, size_t ws_size,
                              hipStream_t stream) {
    const float* W0  = (const float*)d_in[0];
    const float* b0  = (const float*)d_in[1];
    const float* W1  = (const float*)d_in[2];
    const float* b1  = (const float*)d_in[3];
    const float* W2  = (const float*)d_in[4];
    const float* b2  = (const float*)d_in[5];
    const float* W3  = (const float*)d_in[6];
    const float* b3  = (const float*)d_in[7];
    const float* W4  = (const float*)d_in[8];
    const float* b4  = (const float*)d_in[9];
    const float* y0p = (const float*)d_in[10];
    const float* dW  = (const float*)d_in[11];
    float* slots = (float*)d_ws;

    (void)hipMemsetAsync(d_ws, 0, 256 * sizeof(float), stream);

    dim3 grid(BATCH / 64);   // 2048 blocks x 4 independent waves (16 samples)
    dim3 block(256);
    fbsnn_kernel<<<grid, block, 0, stream>>>(W0, b0, W1, b1, W2, b2, W3, b3,
                                             W4, b4, y0p, dW, slots);
    finish_kernel<<<1, 64, 0, stream>>>(slots, (float*)d_out);
}